// Round 7
// baseline (549.585 us; speedup 1.0000x reference)
//
#include <hip/hip_runtime.h>
#include <hip/hip_bf16.h>
#include <cstdint>

// B=8, N=1024, T=32, F=64.  256 independent attention problems of (N=1024, F=64).
// out = relu( ((adj ⊙ softmax(X Xᵀ/8)) X / 8) θᵀ ) per (b,t); X row n = x[b,n,t,:].
// fp32 I/O. Round-12: occupancy attack. Rounds 4-6 sit at 16 waves/CU (VGPR 80-92
// > 64 halves residency, m69 step); all pipes <45% busy -> latency-bound. Restructure
// to 16 waves x 1024 threads, each wave owns 16 queries (one s-slice): persistent
// regs ~48 (acc 16 + bq 8 + pk 8 + g 4 + misc), targeted at the 64-VGPR cap via
// __launch_bounds__(1024, 8) -> 32 waves/CU, 2 blocks/CU. adj prefetch dropped
// (in-loop early-issue loads; 2x TLP covers L2 latency) to fit the cap.
// K=16 PV/epilogue (no P-exchange), double-buffered Xkh/Xv, one barrier/iter,
// builtin exp2, SC folded into Q — all unchanged from verified round-11.
// LDS = 32 KB. Swizzles re-derived for the 1024-thread stager (4-access/bank min).
#define NN 1024
#define ROWSTRIDE 2048   // NT*NF

typedef __attribute__((ext_vector_type(8))) short bf16x8;
typedef __attribute__((ext_vector_type(4))) short bf16x4;
typedef __attribute__((ext_vector_type(4))) float f32x4;
typedef unsigned short u16;

#if __has_builtin(__builtin_amdgcn_exp2f)
#define EXP2(x) __builtin_amdgcn_exp2f(x)
#else
#define EXP2(x) exp2f(x)
#endif

__device__ __forceinline__ f32x4 mfma_bf16(bf16x8 a, bf16x8 b, f32x4 c) {
    return __builtin_amdgcn_mfma_f32_16x16x32_bf16(a, b, c, 0, 0, 0);
}

// K=16 bf16 MFMA: builtin name cascade (new-style, gfx90a "_1k", asm fallback).
#if __has_builtin(__builtin_amdgcn_mfma_f32_16x16x16_bf16)
#define MFMA16(a, b, c) __builtin_amdgcn_mfma_f32_16x16x16_bf16(a, b, c, 0, 0, 0)
#elif __has_builtin(__builtin_amdgcn_mfma_f32_16x16x16bf16_1k)
#define MFMA16(a, b, c) __builtin_amdgcn_mfma_f32_16x16x16bf16_1k(a, b, c, 0, 0, 0)
#else
__device__ __forceinline__ f32x4 mfma16_fb(bf16x4 a, bf16x4 b, f32x4 c) {
    f32x4 d;
    asm("v_mfma_f32_16x16x16_bf16 %0, %1, %2, %3\n\ts_nop 7\n\ts_nop 7"
        : "=v"(d) : "v"(a), "v"(b), "v"(c));
    return d;
}
#define MFMA16(a, b, c) mfma16_fb(a, b, c)
#endif

__device__ __forceinline__ float bf16_to_f32(u16 h) {
    unsigned int u = ((unsigned int)h) << 16;
    return __builtin_bit_cast(float, u);
}
__device__ __forceinline__ u16 f32_to_bf16(float f) {
    __hip_bfloat16 h = __float2bfloat16(f);   // RNE
    return __builtin_bit_cast(u16, h);
}
__device__ __forceinline__ uint32_t pack2(float a, float b) {
    return (uint32_t)f32_to_bf16(a) | ((uint32_t)f32_to_bf16(b) << 16);
}

// adj in-loop load traits: one 4-col chunk per kt
template <typename AT> struct AdjT;
template <> struct AdjT<u16>   { using V = ushort4; };
template <> struct AdjT<float> { using V = float4;  };
__device__ __forceinline__ void cvt4(ushort4 v, float* o) {
    o[0] = bf16_to_f32(v.x); o[1] = bf16_to_f32(v.y);
    o[2] = bf16_to_f32(v.z); o[3] = bf16_to_f32(v.w);
}
__device__ __forceinline__ void cvt4(float4 v, float* o) {
    o[0] = v.x; o[1] = v.y; o[2] = v.z; o[3] = v.w;
}

__global__ void cvt_adj_kernel(const float* __restrict__ a, u16* __restrict__ o) {
    int i = (blockIdx.x * 256 + threadIdx.x) * 4;
    float4 v = *(const float4*)(a + i);
    ushort4 h;
    h.x = f32_to_bf16(v.x); h.y = f32_to_bf16(v.y);
    h.z = f32_to_bf16(v.z); h.w = f32_to_bf16(v.w);
    *(ushort4*)(o + i) = h;
}

// MFMA layouts (HW-verified):
//   16x16x32: A[m=lane&15][k=(lane>>4)*8+r]  B[k=(lane>>4)*8+r][n=lane&15]
//   16x16x16: A[m=lane&15][k=(lane>>4)*4+r]  B[k=(lane>>4)*4+r][n=lane&15]
//   C/D (both): D[row=(lane>>4)*4+reg][col=lane&15]
// => C/D of a QK mfma, bf16-packed per 4-row group, is directly a K=16 B-frag.

// stage 4 floats of one 64x64 X-tile (1024-thread stager: js=tid>>4, fcs4=tid&15):
// row-major Xkh (uint2, phys chunk = (fcs4>>1)^(js&7), half fcs4&1) +
// transposed Xv (4x b16, phys chunk = (js>>3)^(f&7)^(f>>3), elem js&7)
__device__ __forceinline__ void stage_tile(u16* __restrict__ xk, u16* __restrict__ xv,
                                           float4 g, int js, int fcs4) {
    u16 h0 = f32_to_bf16(g.x), h1 = f32_to_bf16(g.y);
    u16 h2 = f32_to_bf16(g.z), h3 = f32_to_bf16(g.w);
    uint2 w;
    w.x = (uint32_t)h0 | ((uint32_t)h1 << 16);
    w.y = (uint32_t)h2 | ((uint32_t)h3 << 16);
    *(uint2*)&xk[js * 64 + ((((fcs4 >> 1) ^ (js & 7)) << 3) | ((fcs4 & 1) << 2))] = w;
    const int f0 = fcs4 * 4;
    const int mc = js >> 3;
    u16 hh[4] = {h0, h1, h2, h3};
#pragma unroll
    for (int r = 0; r < 4; ++r) {
        const int f = f0 + r;
        xv[f * 64 + ((mc ^ (f & 7) ^ (f >> 3)) << 3) + (js & 7)] = hh[r];
    }
}

template <typename AT>
__launch_bounds__(1024, 8)
__global__ void attn_gcn_kernel(const float* __restrict__ x,
                                const AT*   __restrict__ adj,
                                const float* __restrict__ theta,
                                float* __restrict__ out)
{
    // Double-buffered: stage(kb+1) writes buf[cur^1] while QK/PV read buf[cur].
    __shared__ __align__(16) u16 Xkh[2][64 * 64];      // 16384 B
    __shared__ __align__(16) u16 Xv [2][64 * 64];      // 16384 B   (total 32 KB)

    const int tid  = threadIdx.x;
    const int lane = tid & 63;
    const int wid  = tid >> 6;        // 0..15
    const int l16  = lane & 15;
    const int q    = lane >> 4;

    const int blk = blockIdx.x;
    const int p   = blk & 255;        // problem (b*32+t); qb-major for adj L2 reuse
    const int qb  = blk >> 8;
    const int b   = p >> 5;
    const int t   = p & 31;

    const float* xb = x + (size_t)b * NN * ROWSTRIDE + (size_t)t * 64;
    const int    i0 = qb * 256 + wid * 16;   // wave's 16 query rows

    const float SC = 0.125f * 1.44269504088896340736f;   // exp(S/8)=exp2(S*SC)

    // ---- Q B-frags (pre-scaled by SC) + exact row norm (fp32, scaled)
    bf16x8 bq[2];
    float  nrm = 0.f;
#pragma unroll
    for (int kc = 0; kc < 2; ++kc) {
        const float* qp = xb + (size_t)(i0 + l16) * ROWSTRIDE + kc * 32 + q * 8;
        float4 v0 = *(const float4*)qp;
        float4 v1 = *(const float4*)(qp + 4);
        float vv[8] = {v0.x, v0.y, v0.z, v0.w, v1.x, v1.y, v1.z, v1.w};
        union { u16 h[8]; bf16x8 v; } H;
#pragma unroll
        for (int r = 0; r < 8; ++r) {
            nrm += vv[r] * vv[r];
            H.h[r] = f32_to_bf16(vv[r] * SC);
        }
        bq[kc] = H.v;
    }
    nrm += __shfl_xor(nrm, 16);
    nrm += __shfl_xor(nrm, 32);
    nrm *= SC;      // diag substitution directly in exp2 domain

    // diagonal location: key n lands in k-tile kbd, sub-tile ktd,
    // C/D lane q == l16>>2, element r == l16&3   (i0 is a multiple of 16)
    const int kbd = i0 >> 6, ktd = (i0 >> 4) & 3;
    const bool dlane = (q == (l16 >> 2));
    const int  dr    = l16 & 3;

    // per-lane adj row base (n = i0 + l16); loads issued early each iter (no
    // register prefetch: saves 8 VGPRs for the 64-cap, TLP covers L2 latency)
    const AT* adjr = adj + (size_t)(i0 + l16) * NN + q * 4;

    const f32x4 zero4 = {0.f, 0.f, 0.f, 0.f};
    f32x4 acc[4];
#pragma unroll
    for (int ft = 0; ft < 4; ++ft) acc[ft] = zero4;
    float dp = 0.f;

    // staging role: key row js, f-chunk fcs4 (4 floats)
    const int js = tid >> 4, fcs4 = tid & 15;
    const float* gbase = xb + (size_t)js * ROWSTRIDE + fcs4 * 4;

    // ---- prologue: stage kb=0 into buf0; pipeline g (X tile kb+1)
    stage_tile(Xkh[0], Xv[0], *(const float4*)gbase, js, fcs4);
    float4 g = *(const float4*)(gbase + (size_t)64 * ROWSTRIDE);
    __syncthreads();

#pragma unroll 1
    for (int kb = 0; kb < 16; ++kb) {
        const int cur = kb & 1;
        const u16* xk = Xkh[cur];
        const u16* xv = Xv[cur];
        const int j0 = kb * 64;

        // ---- adj loads issued first (consumed after MFMAs+exp; vmcnt covered)
        typename AdjT<AT>::V a_t[4];
#pragma unroll
        for (int kt = 0; kt < 4; ++kt)
            a_t[kt] = *(const typename AdjT<AT>::V*)(adjr + j0 + kt * 16);

        // ---- Sᵀ = K·Qᵀ (bf16) -> exact-diag fix -> exp -> ×adj -> packed P
        uint32_t pk0[4], pk1[4];   // [kt]: keys 16kt+4q+{0,1} / {2,3}
#pragma unroll
        for (int kt = 0; kt < 4; ++kt) {
            const int base = (kt * 16 + l16) * 64;   // (kt*16+l16)&7 == l16&7
            const int sw   = l16 & 7;
            bf16x8 akh0 = *(const bf16x8*)&xk[base + ((q ^ sw) << 3)];
            bf16x8 akh1 = *(const bf16x8*)&xk[base + (((4 + q) ^ sw) << 3)];
            f32x4 z = mfma_bf16(akh0, bq[0], zero4);
            z = mfma_bf16(akh1, bq[1], z);
            // exact diagonal substitution (already in exp2 domain)
            if (kb == kbd && kt == ktd && dlane) {
#pragma unroll
                for (int r = 0; r < 4; ++r)
                    if (r == dr) z[r] = nrm;
            }
            float av[4];
            cvt4(a_t[kt], av);
            float e0 = EXP2(z[0]), e1 = EXP2(z[1]);
            float e2 = EXP2(z[2]), e3 = EXP2(z[3]);
            dp += (e0 + e1) + (e2 + e3);
            pk0[kt] = pack2(e0 * av[0], e1 * av[1]);
            pk1[kt] = pack2(e2 * av[2], e3 * av[3]);
        }

        // ---- stage tile kb+1 into the idle buffer (g loaded one iter ago)
        if (kb < 15)
            stage_tile(Xkh[cur ^ 1], Xv[cur ^ 1], g, js, fcs4);

        // ---- issue global X load for tile kb+2
        if (kb < 14)
            g = *(const float4*)(gbase + (size_t)(kb + 2) * 64 * ROWSTRIDE);

        // ---- PV (K=16): aggᵀ[f][n] += Xv(A) · P(B); B = pk pairs, no exchange.
        //      A[m=f-sub l16][k=key 4q+r]: keys 16kt+4q+{0..3} from Xv chunk
        //      mc=2kt+(q>>1), half (q&1)*4; phys chunk = mc ^ (f&7) ^ (f>>3).
#pragma unroll
        for (int kt = 0; kt < 4; ++kt) {
            union { uint32_t u[2]; bf16x4 v; } B0;
            B0.u[0] = pk0[kt]; B0.u[1] = pk1[kt];
            const int mc = (kt << 1) | (q >> 1);
#pragma unroll
            for (int ft = 0; ft < 4; ++ft) {
                const int f     = ft * 16 + l16;
                const int chunk = mc ^ (l16 & 7) ^ ((ft << 1) | (l16 >> 3));
                const bf16x4 a  = *(const bf16x4*)
                    &xv[f * 64 + (chunk << 3) + ((q & 1) << 2)];
                acc[ft] = MFMA16(a, B0.v, acc[ft]);
            }
        }
        __syncthreads();   // publish stage(kb+1); all buf[cur] reads drained
    }

    // ---- denominator reduce: lanes {l16 + 16q} share query n
    float v = dp;
    v += __shfl_xor(v, 16);
    v += __shfl_xor(v, 32);
    const float inv8d = 1.0f / (8.0f * v);   // extra 1/sqrt(F) from GCN forward

    // ---- epilogue (K=16): outᵀ = θ(A) · aggᵀ(B); agg C/D IS the B-frag.
    //      A[m=fo l16][k=f' 4q+r] = θ[fot*16+l16][ktf*16+4q+r]
    bf16x4 bg[4];
#pragma unroll
    for (int ktf = 0; ktf < 4; ++ktf) {
        union { uint32_t u[2]; bf16x4 v; } G;
        G.u[0] = pack2(acc[ktf][0] * inv8d, acc[ktf][1] * inv8d);
        G.u[1] = pack2(acc[ktf][2] * inv8d, acc[ktf][3] * inv8d);
        bg[ktf] = G.v;
    }

    float* ob = out + (size_t)b * NN * ROWSTRIDE + (size_t)t * 64
                    + (size_t)(i0 + l16) * ROWSTRIDE + q * 4;
#pragma unroll
    for (int fot = 0; fot < 4; ++fot) {
        f32x4 z = zero4;
#pragma unroll
        for (int ktf = 0; ktf < 4; ++ktf) {
            const float* tp = theta + (fot * 16 + l16) * 64 + ktf * 16 + q * 4;
            float4 tv = *(const float4*)tp;
            union { u16 h[4]; bf16x4 b; } H;
            H.h[0] = f32_to_bf16(tv.x); H.h[1] = f32_to_bf16(tv.y);
            H.h[2] = f32_to_bf16(tv.z); H.h[3] = f32_to_bf16(tv.w);
            z = MFMA16(H.b, bg[ktf], z);
        }
        float4 o4;
        o4.x = z[0] > 0.f ? z[0] : 0.f;
        o4.y = z[1] > 0.f ? z[1] : 0.f;
        o4.z = z[2] > 0.f ? z[2] : 0.f;
        o4.w = z[3] > 0.f ? z[3] : 0.f;
        *(float4*)(ob + fot * 16) = o4;
    }
}

extern "C" void kernel_launch(void* const* d_in, const int* in_sizes, int n_in,
                              void* d_out, int out_size, void* d_ws, size_t ws_size,
                              hipStream_t stream) {
    const float* x     = (const float*)d_in[0];   // (8,1024,32,64) fp32
    const float* adj   = (const float*)d_in[1];   // (1024,1024)   fp32
    const float* theta = (const float*)d_in[2];   // (64,64)       fp32
    float* o = (float*)d_out;                     // (8,1024,32,64) fp32

    const size_t adj_bytes = (size_t)NN * NN * sizeof(u16);
    if (ws_size >= adj_bytes) {
        u16* adjb = (u16*)d_ws;
        cvt_adj_kernel<<<dim3(NN * NN / (256 * 4)), dim3(256), 0, stream>>>(adj, adjb);
        attn_gcn_kernel<u16><<<dim3(1024), dim3(1024), 0, stream>>>(x, adjb, theta, o);
    } else {
        attn_gcn_kernel<float><<<dim3(1024), dim3(1024), 0, stream>>>(x, adj, theta, o);
    }
}

// Round 8
// 328.682 us; speedup vs baseline: 1.6721x; 1.6721x over previous
//
#include <hip/hip_runtime.h>
#include <hip/hip_bf16.h>
#include <cstdint>

// B=8, N=1024, T=32, F=64.  256 independent attention problems of (N=1024, F=64).
// out = relu( ((adj ⊙ softmax(X Xᵀ/8)) X / 8) θᵀ ) per (b,t); X row n = x[b,n,t,:].
// fp32 I/O. Round-13: round-7's 16-queries/wave structure was right; its failure
// was __launch_bounds__ semantics. Evidence across rounds: HIP arg2 acts CUDA-style
// (min blocks/CU): (512,4)->64 regs, (512,2)->128, (1024,8)->16->clamped 32 (round-7's
// VGPR=32 + 440MB spill). Fix: (1024,2) -> 8 waves/EU -> 64-reg cap, 32 waves/CU
// (2x round-6 residency; all pipes were <45% busy = latency-bound).
// Pressure/VALU trims for the 64-reg budget: x pre-converted to bf16 in workspace
// (staging = pure u16 copy, g prefetch 4->2 regs, -6 VALU/thread/iter, identical
// numerics: same RNE cvt; Q frags + exact diag still from fp32 x), adj loads
// pipelined 1-kt-ahead (transient 4 regs, not 8).
// K=16 PV/epilogue (no P-exchange), double-buffered Xkh/Xv, one barrier/iter,
// builtin exp2, SC folded into Q — all verified rounds 6-7. LDS = 32 KB.
#define NN 1024
#define ROWSTRIDE 2048   // NT*NF

typedef __attribute__((ext_vector_type(8))) short bf16x8;
typedef __attribute__((ext_vector_type(4))) short bf16x4;
typedef __attribute__((ext_vector_type(4))) float f32x4;
typedef unsigned short u16;

#if __has_builtin(__builtin_amdgcn_exp2f)
#define EXP2(x) __builtin_amdgcn_exp2f(x)
#else
#define EXP2(x) exp2f(x)
#endif

__device__ __forceinline__ f32x4 mfma_bf16(bf16x8 a, bf16x8 b, f32x4 c) {
    return __builtin_amdgcn_mfma_f32_16x16x32_bf16(a, b, c, 0, 0, 0);
}

// K=16 bf16 MFMA: builtin name cascade (new-style, gfx90a "_1k", asm fallback).
#if __has_builtin(__builtin_amdgcn_mfma_f32_16x16x16_bf16)
#define MFMA16(a, b, c) __builtin_amdgcn_mfma_f32_16x16x16_bf16(a, b, c, 0, 0, 0)
#elif __has_builtin(__builtin_amdgcn_mfma_f32_16x16x16bf16_1k)
#define MFMA16(a, b, c) __builtin_amdgcn_mfma_f32_16x16x16bf16_1k(a, b, c, 0, 0, 0)
#else
__device__ __forceinline__ f32x4 mfma16_fb(bf16x4 a, bf16x4 b, f32x4 c) {
    f32x4 d;
    asm("v_mfma_f32_16x16x16_bf16 %0, %1, %2, %3\n\ts_nop 7\n\ts_nop 7"
        : "=v"(d) : "v"(a), "v"(b), "v"(c));
    return d;
}
#define MFMA16(a, b, c) mfma16_fb(a, b, c)
#endif

__device__ __forceinline__ float bf16_to_f32(u16 h) {
    unsigned int u = ((unsigned int)h) << 16;
    return __builtin_bit_cast(float, u);
}
__device__ __forceinline__ u16 f32_to_bf16(float f) {
    __hip_bfloat16 h = __float2bfloat16(f);   // RNE
    return __builtin_bit_cast(u16, h);
}
__device__ __forceinline__ uint32_t pack2(float a, float b) {
    return (uint32_t)f32_to_bf16(a) | ((uint32_t)f32_to_bf16(b) << 16);
}

// adj load traits: one 4-col chunk per kt
template <typename AT> struct AdjT;
template <> struct AdjT<u16>   { using V = ushort4; };
template <> struct AdjT<float> { using V = float4;  };
__device__ __forceinline__ void cvt4(ushort4 v, float* o) {
    o[0] = bf16_to_f32(v.x); o[1] = bf16_to_f32(v.y);
    o[2] = bf16_to_f32(v.z); o[3] = bf16_to_f32(v.w);
}
__device__ __forceinline__ void cvt4(float4 v, float* o) {
    o[0] = v.x; o[1] = v.y; o[2] = v.z; o[3] = v.w;
}

// staging-source traits: bf16 x (workspace) or fp32 x (fallback)
template <typename XT> struct XTv;
template <> struct XTv<u16>   { using V = ushort4; };
template <> struct XTv<float> { using V = float4;  };
__device__ __forceinline__ void to_h4(ushort4 v, u16* h) {
    h[0] = v.x; h[1] = v.y; h[2] = v.z; h[3] = v.w;
}
__device__ __forceinline__ void to_h4(float4 v, u16* h) {
    h[0] = f32_to_bf16(v.x); h[1] = f32_to_bf16(v.y);
    h[2] = f32_to_bf16(v.z); h[3] = f32_to_bf16(v.w);
}

__global__ void cvt_adj_kernel(const float* __restrict__ a, u16* __restrict__ o) {
    int i = (blockIdx.x * 256 + threadIdx.x) * 4;
    float4 v = *(const float4*)(a + i);
    ushort4 h;
    h.x = f32_to_bf16(v.x); h.y = f32_to_bf16(v.y);
    h.z = f32_to_bf16(v.z); h.w = f32_to_bf16(v.w);
    *(ushort4*)(o + i) = h;
}

__global__ void cvt_x_kernel(const float* __restrict__ a, u16* __restrict__ o) {
    int i = (blockIdx.x * 256 + threadIdx.x) * 8;
    float4 v0 = *(const float4*)(a + i);
    float4 v1 = *(const float4*)(a + i + 4);
    ushort4 h0, h1;
    h0.x = f32_to_bf16(v0.x); h0.y = f32_to_bf16(v0.y);
    h0.z = f32_to_bf16(v0.z); h0.w = f32_to_bf16(v0.w);
    h1.x = f32_to_bf16(v1.x); h1.y = f32_to_bf16(v1.y);
    h1.z = f32_to_bf16(v1.z); h1.w = f32_to_bf16(v1.w);
    *(ushort4*)(o + i)     = h0;
    *(ushort4*)(o + i + 4) = h1;
}

// MFMA layouts (HW-verified):
//   16x16x32: A[m=lane&15][k=(lane>>4)*8+r]  B[k=(lane>>4)*8+r][n=lane&15]
//   16x16x16: A[m=lane&15][k=(lane>>4)*4+r]  B[k=(lane>>4)*4+r][n=lane&15]
//   C/D (both): D[row=(lane>>4)*4+reg][col=lane&15]
// => C/D of a QK mfma, bf16-packed per 4-row group, is directly a K=16 B-frag.

// stage 4 elems of one 64x64 X-tile (1024-thread stager: js=tid>>4, fcs4=tid&15):
// row-major Xkh (uint2, phys chunk = (fcs4>>1)^(js&7), half fcs4&1) +
// transposed Xv (4x b16, phys chunk = (js>>3)^(f&7)^(f>>3), elem js&7)
template <typename GV>
__device__ __forceinline__ void stage_tile(u16* __restrict__ xk, u16* __restrict__ xv,
                                           GV g, int js, int fcs4) {
    u16 h[4];
    to_h4(g, h);
    uint2 w;
    w.x = (uint32_t)h[0] | ((uint32_t)h[1] << 16);
    w.y = (uint32_t)h[2] | ((uint32_t)h[3] << 16);
    *(uint2*)&xk[js * 64 + ((((fcs4 >> 1) ^ (js & 7)) << 3) | ((fcs4 & 1) << 2))] = w;
    const int f0 = fcs4 * 4;
    const int mc = js >> 3;
#pragma unroll
    for (int r = 0; r < 4; ++r) {
        const int f = f0 + r;
        xv[f * 64 + ((mc ^ (f & 7) ^ (f >> 3)) << 3) + (js & 7)] = h[r];
    }
}

template <typename AT, typename XT>
__launch_bounds__(1024, 2)
__global__ void attn_gcn_kernel(const float* __restrict__ x,
                                const XT*   __restrict__ xs,
                                const AT*   __restrict__ adj,
                                const float* __restrict__ theta,
                                float* __restrict__ out)
{
    // Double-buffered: stage(kb+1) writes buf[cur^1] while QK/PV read buf[cur].
    __shared__ __align__(16) u16 Xkh[2][64 * 64];      // 16384 B
    __shared__ __align__(16) u16 Xv [2][64 * 64];      // 16384 B   (total 32 KB)

    const int tid  = threadIdx.x;
    const int lane = tid & 63;
    const int wid  = tid >> 6;        // 0..15
    const int l16  = lane & 15;
    const int q    = lane >> 4;

    const int blk = blockIdx.x;
    const int p   = blk & 255;        // problem (b*32+t); qb-major for adj L2 reuse
    const int qb  = blk >> 8;
    const int b   = p >> 5;
    const int t   = p & 31;

    const float* xb = x + (size_t)b * NN * ROWSTRIDE + (size_t)t * 64;
    const int    i0 = qb * 256 + wid * 16;   // wave's 16 query rows

    const float SC = 0.125f * 1.44269504088896340736f;   // exp(S/8)=exp2(S*SC)

    // ---- Q B-frags (pre-scaled by SC) + exact row norm (fp32, scaled)
    bf16x8 bq[2];
    float  nrm = 0.f;
#pragma unroll
    for (int kc = 0; kc < 2; ++kc) {
        const float* qp = xb + (size_t)(i0 + l16) * ROWSTRIDE + kc * 32 + q * 8;
        float4 v0 = *(const float4*)qp;
        float4 v1 = *(const float4*)(qp + 4);
        float vv[8] = {v0.x, v0.y, v0.z, v0.w, v1.x, v1.y, v1.z, v1.w};
        union { u16 h[8]; bf16x8 v; } H;
#pragma unroll
        for (int r = 0; r < 8; ++r) {
            nrm += vv[r] * vv[r];
            H.h[r] = f32_to_bf16(vv[r] * SC);
        }
        bq[kc] = H.v;
    }
    nrm += __shfl_xor(nrm, 16);
    nrm += __shfl_xor(nrm, 32);
    nrm *= SC;      // diag substitution directly in exp2 domain

    // diagonal location: key n lands in k-tile kbd, sub-tile ktd,
    // C/D lane q == l16>>2, element r == l16&3   (i0 is a multiple of 16)
    const int kbd = i0 >> 6, ktd = (i0 >> 4) & 3;
    const bool dlane = (q == (l16 >> 2));
    const int  dr    = l16 & 3;

    // per-lane adj row base (n = i0 + l16); loads pipelined 1-kt-ahead in-loop
    const AT* adjr = adj + (size_t)(i0 + l16) * NN + q * 4;

    const f32x4 zero4 = {0.f, 0.f, 0.f, 0.f};
    f32x4 acc[4];
#pragma unroll
    for (int ft = 0; ft < 4; ++ft) acc[ft] = zero4;
    float dp = 0.f;

    // staging role: key row js, 4-elem chunk fcs4
    const int js = tid >> 4, fcs4 = tid & 15;
    const XT* gbase = xs + (size_t)b * NN * ROWSTRIDE + (size_t)t * 64
                         + (size_t)js * ROWSTRIDE + fcs4 * 4;

    // ---- prologue: stage kb=0 into buf0; pipeline g (X tile kb+1)
    stage_tile(Xkh[0], Xv[0], *(const typename XTv<XT>::V*)gbase, js, fcs4);
    typename XTv<XT>::V g = *(const typename XTv<XT>::V*)(gbase + (size_t)64 * ROWSTRIDE);
    __syncthreads();

#pragma unroll 1
    for (int kb = 0; kb < 16; ++kb) {
        const int cur = kb & 1;
        const u16* xk = Xkh[cur];
        const u16* xv = Xv[cur];
        const AT* adjp = adjr + kb * 64;

        // ---- Sᵀ = K·Qᵀ (bf16) -> exact-diag fix -> exp -> ×adj -> packed P
        uint32_t pk0[4], pk1[4];   // [kt]: keys 16kt+4q+{0,1} / {2,3}
        typename AdjT<AT>::V a_nxt = *(const typename AdjT<AT>::V*)adjp;
#pragma unroll
        for (int kt = 0; kt < 4; ++kt) {
            typename AdjT<AT>::V a_cur = a_nxt;
            if (kt < 3)
                a_nxt = *(const typename AdjT<AT>::V*)(adjp + (kt + 1) * 16);
            const int base = (kt * 16 + l16) * 64;   // (kt*16+l16)&7 == l16&7
            const int sw   = l16 & 7;
            bf16x8 akh0 = *(const bf16x8*)&xk[base + ((q ^ sw) << 3)];
            bf16x8 akh1 = *(const bf16x8*)&xk[base + (((4 + q) ^ sw) << 3)];
            f32x4 z = mfma_bf16(akh0, bq[0], zero4);
            z = mfma_bf16(akh1, bq[1], z);
            // exact diagonal substitution (already in exp2 domain)
            if (kb == kbd && kt == ktd && dlane) {
#pragma unroll
                for (int r = 0; r < 4; ++r)
                    if (r == dr) z[r] = nrm;
            }
            float av[4];
            cvt4(a_cur, av);
            float e0 = EXP2(z[0]), e1 = EXP2(z[1]);
            float e2 = EXP2(z[2]), e3 = EXP2(z[3]);
            dp += (e0 + e1) + (e2 + e3);
            pk0[kt] = pack2(e0 * av[0], e1 * av[1]);
            pk1[kt] = pack2(e2 * av[2], e3 * av[3]);
        }

        // ---- stage tile kb+1 into the idle buffer (g loaded one iter ago)
        if (kb < 15)
            stage_tile(Xkh[cur ^ 1], Xv[cur ^ 1], g, js, fcs4);

        // ---- issue global X load for tile kb+2
        if (kb < 14)
            g = *(const typename XTv<XT>::V*)(gbase + (size_t)(kb + 2) * 64 * ROWSTRIDE);

        // ---- PV (K=16): aggᵀ[f][n] += Xv(A) · P(B); B = pk pairs, no exchange.
        //      A[m=f-sub l16][k=key 4q+r]: keys 16kt+4q+{0..3} from Xv chunk
        //      mc=2kt+(q>>1), half (q&1)*4; phys chunk = mc ^ (f&7) ^ (f>>3).
#pragma unroll
        for (int kt = 0; kt < 4; ++kt) {
            union { uint32_t u[2]; bf16x4 v; } B0;
            B0.u[0] = pk0[kt]; B0.u[1] = pk1[kt];
            const int mc = (kt << 1) | (q >> 1);
#pragma unroll
            for (int ft = 0; ft < 4; ++ft) {
                const int f     = ft * 16 + l16;
                const int chunk = mc ^ (l16 & 7) ^ ((ft << 1) | (l16 >> 3));
                const bf16x4 a  = *(const bf16x4*)
                    &xv[f * 64 + (chunk << 3) + ((q & 1) << 2)];
                acc[ft] = MFMA16(a, B0.v, acc[ft]);
            }
        }
        __syncthreads();   // publish stage(kb+1); all buf[cur] reads drained
    }

    // ---- denominator reduce: lanes {l16 + 16q} share query n
    float v = dp;
    v += __shfl_xor(v, 16);
    v += __shfl_xor(v, 32);
    const float inv8d = 1.0f / (8.0f * v);   // extra 1/sqrt(F) from GCN forward

    // ---- epilogue (K=16): outᵀ = θ(A) · aggᵀ(B); agg C/D IS the B-frag.
    //      A[m=fo l16][k=f' 4q+r] = θ[fot*16+l16][ktf*16+4q+r]
    bf16x4 bg[4];
#pragma unroll
    for (int ktf = 0; ktf < 4; ++ktf) {
        union { uint32_t u[2]; bf16x4 v; } G;
        G.u[0] = pack2(acc[ktf][0] * inv8d, acc[ktf][1] * inv8d);
        G.u[1] = pack2(acc[ktf][2] * inv8d, acc[ktf][3] * inv8d);
        bg[ktf] = G.v;
    }

    float* ob = out + (size_t)b * NN * ROWSTRIDE + (size_t)t * 64
                    + (size_t)(i0 + l16) * ROWSTRIDE + q * 4;
#pragma unroll
    for (int fot = 0; fot < 4; ++fot) {
        f32x4 z = zero4;
#pragma unroll
        for (int ktf = 0; ktf < 4; ++ktf) {
            const float* tp = theta + (fot * 16 + l16) * 64 + ktf * 16 + q * 4;
            float4 tv = *(const float4*)tp;
            union { u16 h[4]; bf16x4 b; } H;
            H.h[0] = f32_to_bf16(tv.x); H.h[1] = f32_to_bf16(tv.y);
            H.h[2] = f32_to_bf16(tv.z); H.h[3] = f32_to_bf16(tv.w);
            z = MFMA16(H.b, bg[ktf], z);
        }
        float4 o4;
        o4.x = z[0] > 0.f ? z[0] : 0.f;
        o4.y = z[1] > 0.f ? z[1] : 0.f;
        o4.z = z[2] > 0.f ? z[2] : 0.f;
        o4.w = z[3] > 0.f ? z[3] : 0.f;
        *(float4*)(ob + fot * 16) = o4;
    }
}

extern "C" void kernel_launch(void* const* d_in, const int* in_sizes, int n_in,
                              void* d_out, int out_size, void* d_ws, size_t ws_size,
                              hipStream_t stream) {
    const float* x     = (const float*)d_in[0];   // (8,1024,32,64) fp32
    const float* adj   = (const float*)d_in[1];   // (1024,1024)   fp32
    const float* theta = (const float*)d_in[2];   // (64,64)       fp32
    float* o = (float*)d_out;                     // (8,1024,32,64) fp32

    const size_t adj_bytes = (size_t)NN * NN * sizeof(u16);
    const size_t x_elems   = (size_t)8 * NN * 32 * 64;
    const size_t xh_bytes  = x_elems * sizeof(u16);

    if (ws_size >= adj_bytes + xh_bytes) {
        u16* adjb = (u16*)d_ws;
        u16* xh   = (u16*)((char*)d_ws + adj_bytes);
        cvt_adj_kernel<<<dim3(NN * NN / (256 * 4)), dim3(256), 0, stream>>>(adj, adjb);
        cvt_x_kernel<<<dim3(x_elems / (256 * 8)), dim3(256), 0, stream>>>(x, xh);
        attn_gcn_kernel<u16, u16><<<dim3(1024), dim3(1024), 0, stream>>>(x, xh, adjb, theta, o);
    } else if (ws_size >= adj_bytes) {
        u16* adjb = (u16*)d_ws;
        cvt_adj_kernel<<<dim3(NN * NN / (256 * 4)), dim3(256), 0, stream>>>(adj, adjb);
        attn_gcn_kernel<u16, float><<<dim3(1024), dim3(1024), 0, stream>>>(x, x, adjb, theta, o);
    } else {
        attn_gcn_kernel<float, float><<<dim3(1024), dim3(1024), 0, stream>>>(x, x, adj, theta, o);
    }
}

// Round 9
// 275.590 us; speedup vs baseline: 1.9942x; 1.1927x over previous
//
#include <hip/hip_runtime.h>
#include <hip/hip_bf16.h>
#include <cstdint>

// B=8, N=1024, T=32, F=64.  256 independent attention problems of (N=1024, F=64).
// out = relu( ((adj ⊙ softmax(X Xᵀ/8)) X / 8) θᵀ ) per (b,t); X row n = x[b,n,t,:].
// fp32 I/O. Round-14: software-pipeline the verified round-11 (215 µs) structure.
// Rounds 6/8 A/B showed occupancy x per-query-LDS-cost trade off to a wash; every
// pipe <45% -> the limiter is the serial QK->softmax->PV chain per iteration.
// Fix: PV lags one K-tile (iter kb runs QK+softmax(kb) ∥ PV(kb-1)) so the exp/pack
// VALU chain and the PV MFMA/LDS stream interleave within a wave (ILP). Xv becomes
// 3-deep (PV reads kb-1 while kb+1 stages; distance 2 mod 3 = no collision), pk
// double-buffered in regs (+16 VGPR, budget 128). s_setprio(1) wraps the pure-MFMA
// PV cluster (T5: waves at different phases). bf16-x workspace staging kept from
// round-13 (FETCH 144->102 MB). 32 queries/wave, 512 thr, launch_bounds(512,2).
// LDS = 40 KB (Xkh 2x8K + Xv 3x8K); 2 blocks/CU (thread-capped).
#define NN 1024
#define ROWSTRIDE 2048   // NT*NF

typedef __attribute__((ext_vector_type(8))) short bf16x8;
typedef __attribute__((ext_vector_type(4))) short bf16x4;
typedef __attribute__((ext_vector_type(4))) float f32x4;
typedef unsigned short u16;

#if __has_builtin(__builtin_amdgcn_exp2f)
#define EXP2(x) __builtin_amdgcn_exp2f(x)
#else
#define EXP2(x) exp2f(x)
#endif

__device__ __forceinline__ f32x4 mfma_bf16(bf16x8 a, bf16x8 b, f32x4 c) {
    return __builtin_amdgcn_mfma_f32_16x16x32_bf16(a, b, c, 0, 0, 0);
}

// K=16 bf16 MFMA: builtin name cascade (new-style, gfx90a "_1k", asm fallback).
#if __has_builtin(__builtin_amdgcn_mfma_f32_16x16x16_bf16)
#define MFMA16(a, b, c) __builtin_amdgcn_mfma_f32_16x16x16_bf16(a, b, c, 0, 0, 0)
#elif __has_builtin(__builtin_amdgcn_mfma_f32_16x16x16bf16_1k)
#define MFMA16(a, b, c) __builtin_amdgcn_mfma_f32_16x16x16bf16_1k(a, b, c, 0, 0, 0)
#else
__device__ __forceinline__ f32x4 mfma16_fb(bf16x4 a, bf16x4 b, f32x4 c) {
    f32x4 d;
    asm("v_mfma_f32_16x16x16_bf16 %0, %1, %2, %3\n\ts_nop 7\n\ts_nop 7"
        : "=v"(d) : "v"(a), "v"(b), "v"(c));
    return d;
}
#define MFMA16(a, b, c) mfma16_fb(a, b, c)
#endif

__device__ __forceinline__ float bf16_to_f32(u16 h) {
    unsigned int u = ((unsigned int)h) << 16;
    return __builtin_bit_cast(float, u);
}
__device__ __forceinline__ u16 f32_to_bf16(float f) {
    __hip_bfloat16 h = __float2bfloat16(f);   // RNE
    return __builtin_bit_cast(u16, h);
}
__device__ __forceinline__ uint32_t pack2(float a, float b) {
    return (uint32_t)f32_to_bf16(a) | ((uint32_t)f32_to_bf16(b) << 16);
}

// adj vector-prefetch traits: one 4-col chunk per (s,kt)
template <typename AT> struct AdjT;
template <> struct AdjT<u16>   { using V = ushort4; };
template <> struct AdjT<float> { using V = float4;  };
__device__ __forceinline__ void cvt4(ushort4 v, float* o) {
    o[0] = bf16_to_f32(v.x); o[1] = bf16_to_f32(v.y);
    o[2] = bf16_to_f32(v.z); o[3] = bf16_to_f32(v.w);
}
__device__ __forceinline__ void cvt4(float4 v, float* o) {
    o[0] = v.x; o[1] = v.y; o[2] = v.z; o[3] = v.w;
}

// staging-source traits: bf16 x (workspace) or fp32 x (fallback)
template <typename XT> struct XSrc;
template <> struct XSrc<u16> {
    typedef uint4 V;
    union H8 { u16 h[8]; uint4 u; };
    static __device__ __forceinline__ V load(const u16* p) { return *(const uint4*)p; }
    static __device__ __forceinline__ H8 unpack(V v) { H8 r; r.u = v; return r; }
};
template <> struct XSrc<float> {
    struct V { float4 a, b; };
    union H8 { u16 h[8]; uint4 u; };
    static __device__ __forceinline__ V load(const float* p) {
        V r; r.a = *(const float4*)p; r.b = *(const float4*)(p + 4); return r;
    }
    static __device__ __forceinline__ H8 unpack(V v) {
        H8 r;
        r.h[0] = f32_to_bf16(v.a.x); r.h[1] = f32_to_bf16(v.a.y);
        r.h[2] = f32_to_bf16(v.a.z); r.h[3] = f32_to_bf16(v.a.w);
        r.h[4] = f32_to_bf16(v.b.x); r.h[5] = f32_to_bf16(v.b.y);
        r.h[6] = f32_to_bf16(v.b.z); r.h[7] = f32_to_bf16(v.b.w);
        return r;
    }
};

__global__ void cvt_adj_kernel(const float* __restrict__ a, u16* __restrict__ o) {
    int i = (blockIdx.x * 256 + threadIdx.x) * 4;
    float4 v = *(const float4*)(a + i);
    ushort4 h;
    h.x = f32_to_bf16(v.x); h.y = f32_to_bf16(v.y);
    h.z = f32_to_bf16(v.z); h.w = f32_to_bf16(v.w);
    *(ushort4*)(o + i) = h;
}

__global__ void cvt_x_kernel(const float* __restrict__ a, u16* __restrict__ o) {
    int i = (blockIdx.x * 256 + threadIdx.x) * 8;
    float4 v0 = *(const float4*)(a + i);
    float4 v1 = *(const float4*)(a + i + 4);
    ushort4 h0, h1;
    h0.x = f32_to_bf16(v0.x); h0.y = f32_to_bf16(v0.y);
    h0.z = f32_to_bf16(v0.z); h0.w = f32_to_bf16(v0.w);
    h1.x = f32_to_bf16(v1.x); h1.y = f32_to_bf16(v1.y);
    h1.z = f32_to_bf16(v1.z); h1.w = f32_to_bf16(v1.w);
    *(ushort4*)(o + i)     = h0;
    *(ushort4*)(o + i + 4) = h1;
}

// MFMA layouts (HW-verified):
//   16x16x32: A[m=lane&15][k=(lane>>4)*8+r]  B[k=(lane>>4)*8+r][n=lane&15]
//   16x16x16: A[m=lane&15][k=(lane>>4)*4+r]  B[k=(lane>>4)*4+r][n=lane&15]
//   C/D (both): D[row=(lane>>4)*4+reg][col=lane&15]
// => C/D of a QK mfma, bf16-packed per 4-row group, is directly a K=16 B-frag.

// stage one 64x64 X-tile (512-thread stager: js=tid>>3, fcs=tid&7, 8 f-elems):
// row-major Xkh (uint4, phys chunk = fcs^(js&7)) +
// transposed Xv (8x b16, phys chunk = (js>>3)^f(cs)... = (wxf^r), elem js&7)
template <typename XS>
__device__ __forceinline__ void stage_tile(u16* __restrict__ xk, u16* __restrict__ xv,
                                           typename XS::V g, int js, int fcs, int wxf) {
    typename XS::H8 H = XS::unpack(g);
    *(uint4*)&xk[js * 64 + ((fcs ^ (js & 7)) << 3)] = H.u;
#pragma unroll
    for (int r = 0; r < 8; ++r)
        xv[(fcs * 8 + r) * 64 + ((wxf ^ r) << 3) + (js & 7)] = H.h[r];
}

template <typename AT, typename XT>
__launch_bounds__(512, 2)
__global__ void attn_gcn_kernel(const float* __restrict__ x,
                                const XT*   __restrict__ xs,
                                const AT*   __restrict__ adj,
                                const float* __restrict__ theta,
                                float* __restrict__ out)
{
    // Xkh double-buffered (QK cur + stage next); Xv TRIPLE-buffered (PV lags one
    // tile: stage writes (kb+1)%3 while PV reads (kb-1)%3 — distance 2 mod 3).
    __shared__ __align__(16) u16 Xkh[2][64 * 64];      // 16384 B
    __shared__ __align__(16) u16 Xv [3][64 * 64];      // 24576 B   (total 40 KB)

    const int tid  = threadIdx.x;
    const int lane = tid & 63;
    const int wid  = tid >> 6;
    const int l16  = lane & 15;
    const int q    = lane >> 4;

    const int blk = blockIdx.x;
    const int p   = blk & 255;        // problem (b*32+t); qb-major for adj L2 reuse
    const int qb  = blk >> 8;
    const int b   = p >> 5;
    const int t   = p & 31;

    const float* xb = x + (size_t)b * NN * ROWSTRIDE + (size_t)t * 64;
    const int    i0 = qb * 256 + wid * 32;   // wave's 32 query rows

    const float SC = 0.125f * 1.44269504088896340736f;   // exp(S/8)=exp2(S*SC)

    // ---- Q B-frags (pre-scaled by SC) + exact row norms (fp32, scaled)
    bf16x8 bq[2][2];
    float  nrm[2] = {0.f, 0.f};
#pragma unroll
    for (int s = 0; s < 2; ++s) {
#pragma unroll
        for (int kc = 0; kc < 2; ++kc) {
            const float* qp = xb + (size_t)(i0 + s * 16 + l16) * ROWSTRIDE + kc * 32 + q * 8;
            float4 v0 = *(const float4*)qp;
            float4 v1 = *(const float4*)(qp + 4);
            float vv[8] = {v0.x, v0.y, v0.z, v0.w, v1.x, v1.y, v1.z, v1.w};
            union { u16 h[8]; bf16x8 v; } H;
#pragma unroll
            for (int r = 0; r < 8; ++r) {
                nrm[s] += vv[r] * vv[r];
                H.h[r] = f32_to_bf16(vv[r] * SC);
            }
            bq[s][kc] = H.v;
        }
        nrm[s] += __shfl_xor(nrm[s], 16);
        nrm[s] += __shfl_xor(nrm[s], 32);
        nrm[s] *= SC;      // diag substitution directly in exp2 domain
    }
    // diagonal location: key n lands in k-tile kbd[s], sub-tile ktd[s],
    // C/D lane q == l16>>2, element r == l16&3   (i0+16s is a multiple of 16)
    const int kbd0 = (i0) >> 6,        ktd0 = ((i0) >> 4) & 3;
    const int kbd1 = (i0 + 16) >> 6,   ktd1 = ((i0 + 16) >> 4) & 3;
    const bool dlane = (q == (l16 >> 2));
    const int  dr    = l16 & 3;

    // per-lane adj row base (n = i0 + 16s + l16), prefetched one K-tile ahead
    const AT* adjr0 = adj + (size_t)(i0 + l16) * NN;
    const AT* adjr1 = adj + (size_t)(i0 + 16 + l16) * NN;
    typename AdjT<AT>::V a_cur[2][4];

    const f32x4 zero4 = {0.f, 0.f, 0.f, 0.f};
    f32x4 acc[2][4];
#pragma unroll
    for (int s = 0; s < 2; ++s)
#pragma unroll
        for (int ft = 0; ft < 4; ++ft) acc[s][ft] = zero4;
    float dp[2] = {0.f, 0.f};

    // staging role: key row js, f-chunk fcs (8 elems)
    const int js = tid >> 3, fcs = tid & 7;
    const int wxf = (js >> 3) ^ fcs;                 // Xv scatter swizzle base
    using XS = XSrc<XT>;
    const XT* gbase = xs + (size_t)b * NN * ROWSTRIDE + (size_t)t * 64
                         + (size_t)js * ROWSTRIDE + fcs * 8;

    // ---- prologue: stage kb=0; pipeline g (tile kb+1) + adj (kb=0)
    stage_tile<XS>(Xkh[0], Xv[0], XS::load(gbase), js, fcs, wxf);
    typename XS::V g = XS::load(gbase + (size_t)64 * ROWSTRIDE);
#pragma unroll
    for (int s = 0; s < 2; ++s)
#pragma unroll
        for (int kt = 0; kt < 4; ++kt)
            a_cur[s][kt] = *(const typename AdjT<AT>::V*)
                (((s == 0) ? adjr0 : adjr1) + kt * 16 + q * 4);
    __syncthreads();

    // previous tile's packed P (PV lag registers)
    uint32_t pp0[2][4], pp1[2][4];

    // PV body: aggᵀ[f][n] += Xv(A) · P(B), K=16, B straight from pp registers.
    auto pv_step = [&](const u16* __restrict__ xvp) {
        __builtin_amdgcn_s_setprio(1);
#pragma unroll
        for (int kt = 0; kt < 4; ++kt) {
            union { uint32_t u[2]; bf16x4 v; } B0, B1;
            B0.u[0] = pp0[0][kt]; B0.u[1] = pp1[0][kt];
            B1.u[0] = pp0[1][kt]; B1.u[1] = pp1[1][kt];
            const int mc = (kt << 1) | (q >> 1);
#pragma unroll
            for (int ft = 0; ft < 4; ++ft) {
                const int f     = ft * 16 + l16;
                const int chunk = mc ^ (l16 & 7) ^ ((ft << 1) | (l16 >> 3));
                const bf16x4 a  = *(const bf16x4*)
                    &xvp[f * 64 + (chunk << 3) + ((q & 1) << 2)];
                acc[0][ft] = MFMA16(a, B0.v, acc[0][ft]);
                acc[1][ft] = MFMA16(a, B1.v, acc[1][ft]);
            }
        }
        __builtin_amdgcn_s_setprio(0);
    };

    int st3 = 1;   // (kb+1)%3: Xv stage buffer for this iteration
#pragma unroll 1
    for (int kb = 0; kb < 16; ++kb) {
        const u16* xk  = Xkh[kb & 1];
        const int  pv3 = (st3 == 2) ? 0 : st3 + 1;   // (kb-1)%3

        // ---- Sᵀ = K·Qᵀ (bf16) -> exact-diag fix -> exp -> ×adj -> packed P
        uint32_t pk0[2][4], pk1[2][4];   // [s][kt]: keys 16kt+4q+{0,1} / {2,3}
#pragma unroll
        for (int kt = 0; kt < 4; ++kt) {
            const int base = (kt * 16 + l16) * 64;   // (kt*16+l16)&7 == l16&7
            const int sw   = l16 & 7;
            bf16x8 akh0 = *(const bf16x8*)&xk[base + ((q ^ sw) << 3)];
            bf16x8 akh1 = *(const bf16x8*)&xk[base + (((4 + q) ^ sw) << 3)];
#pragma unroll
            for (int s = 0; s < 2; ++s) {
                f32x4 z = mfma_bf16(akh0, bq[s][0], zero4);
                z = mfma_bf16(akh1, bq[s][1], z);
                // exact diagonal substitution (already in exp2 domain)
                const bool isd = (s == 0) ? (kb == kbd0 && kt == ktd0)
                                          : (kb == kbd1 && kt == ktd1);
                if (isd && dlane) {
#pragma unroll
                    for (int r = 0; r < 4; ++r)
                        if (r == dr) z[r] = nrm[s];
                }
                float av[4];
                cvt4(a_cur[s][kt], av);
                float e0 = EXP2(z[0]), e1 = EXP2(z[1]);
                float e2 = EXP2(z[2]), e3 = EXP2(z[3]);
                dp[s] += (e0 + e1) + (e2 + e3);
                pk0[s][kt] = pack2(e0 * av[0], e1 * av[1]);
                pk1[s][kt] = pack2(e2 * av[2], e3 * av[3]);
            }
        }

        // ---- prefetch adj for kb+1
        if (kb < 15) {
            const int jn = (kb + 1) * 64;
#pragma unroll
            for (int s = 0; s < 2; ++s)
#pragma unroll
                for (int kt = 0; kt < 4; ++kt)
                    a_cur[s][kt] = *(const typename AdjT<AT>::V*)
                        (((s == 0) ? adjr0 : adjr1) + jn + kt * 16 + q * 4);
        }

        // ---- stage tile kb+1 (Xkh[(kb+1)&1], Xv[(kb+1)%3]); g loaded 1 iter ago
        if (kb < 15)
            stage_tile<XS>(Xkh[(kb + 1) & 1], Xv[st3], g, js, fcs, wxf);

        // ---- issue global X load for tile kb+2
        if (kb < 14)
            g = XS::load(gbase + (size_t)(kb + 2) * 64 * ROWSTRIDE);

        // ---- PV(kb-1): independent of this iter's softmax -> interleaves with it
        if (kb > 0)
            pv_step(Xv[pv3]);

        // ---- rotate P registers and stage index
#pragma unroll
        for (int s = 0; s < 2; ++s)
#pragma unroll
            for (int kt = 0; kt < 4; ++kt) {
                pp0[s][kt] = pk0[s][kt];
                pp1[s][kt] = pk1[s][kt];
            }
        st3 = (st3 == 2) ? 0 : st3 + 1;
        if (kb < 15) __syncthreads();   // publish stage(kb+1)
    }

    // ---- drain: PV(15); tile 15 was staged into Xv[15%3 == 0] at iter 14
    pv_step(Xv[0]);

    // ---- denominator reduce: lanes {l16 + 16q} share n
    float inv8d[2];
#pragma unroll
    for (int s = 0; s < 2; ++s) {
        float v = dp[s];
        v += __shfl_xor(v, 16);
        v += __shfl_xor(v, 32);
        inv8d[s] = 1.0f / (8.0f * v);   // extra 1/sqrt(F) from GCN forward
    }

    // ---- epilogue (K=16): outᵀ = θ(A) · aggᵀ(B); agg C/D IS the B-frag.
    //      A[m=fo l16][k=f' 4q+r] = θ[fot*16+l16][ktf*16+4q+r]
    bf16x4 th4[4][4];
#pragma unroll
    for (int fot = 0; fot < 4; ++fot)
#pragma unroll
        for (int ktf = 0; ktf < 4; ++ktf) {
            const float* tp = theta + (fot * 16 + l16) * 64 + ktf * 16 + q * 4;
            float4 v = *(const float4*)tp;
            union { u16 h[4]; bf16x4 b; } H;
            H.h[0] = f32_to_bf16(v.x); H.h[1] = f32_to_bf16(v.y);
            H.h[2] = f32_to_bf16(v.z); H.h[3] = f32_to_bf16(v.w);
            th4[fot][ktf] = H.b;
        }

    float* ob = out + (size_t)b * NN * ROWSTRIDE + (size_t)t * 64;
#pragma unroll
    for (int s = 0; s < 2; ++s) {
        bf16x4 bg[4];
#pragma unroll
        for (int ktf = 0; ktf < 4; ++ktf) {
            union { uint32_t u[2]; bf16x4 v; } G;
            G.u[0] = pack2(acc[s][ktf][0] * inv8d[s], acc[s][ktf][1] * inv8d[s]);
            G.u[1] = pack2(acc[s][ktf][2] * inv8d[s], acc[s][ktf][3] * inv8d[s]);
            bg[ktf] = G.v;
        }
        const int n = i0 + s * 16 + l16;
#pragma unroll
        for (int fot = 0; fot < 4; ++fot) {
            f32x4 z = zero4;
#pragma unroll
            for (int ktf = 0; ktf < 4; ++ktf)
                z = MFMA16(th4[fot][ktf], bg[ktf], z);
            float4 o4;
            o4.x = z[0] > 0.f ? z[0] : 0.f;
            o4.y = z[1] > 0.f ? z[1] : 0.f;
            o4.z = z[2] > 0.f ? z[2] : 0.f;
            o4.w = z[3] > 0.f ? z[3] : 0.f;
            *(float4*)(ob + (size_t)n * ROWSTRIDE + fot * 16 + q * 4) = o4;
        }
    }
}

extern "C" void kernel_launch(void* const* d_in, const int* in_sizes, int n_in,
                              void* d_out, int out_size, void* d_ws, size_t ws_size,
                              hipStream_t stream) {
    const float* x     = (const float*)d_in[0];   // (8,1024,32,64) fp32
    const float* adj   = (const float*)d_in[1];   // (1024,1024)   fp32
    const float* theta = (const float*)d_in[2];   // (64,64)       fp32
    float* o = (float*)d_out;                     // (8,1024,32,64) fp32

    const size_t adj_bytes = (size_t)NN * NN * sizeof(u16);
    const size_t x_elems   = (size_t)8 * NN * 32 * 64;
    const size_t xh_bytes  = x_elems * sizeof(u16);

    if (ws_size >= adj_bytes + xh_bytes) {
        u16* adjb = (u16*)d_ws;
        u16* xh   = (u16*)((char*)d_ws + adj_bytes);
        cvt_adj_kernel<<<dim3(NN * NN / (256 * 4)), dim3(256), 0, stream>>>(adj, adjb);
        cvt_x_kernel<<<dim3(x_elems / (256 * 8)), dim3(256), 0, stream>>>(x, xh);
        attn_gcn_kernel<u16, u16><<<dim3(1024), dim3(512), 0, stream>>>(x, xh, adjb, theta, o);
    } else if (ws_size >= adj_bytes) {
        u16* adjb = (u16*)d_ws;
        cvt_adj_kernel<<<dim3(NN * NN / (256 * 4)), dim3(256), 0, stream>>>(adj, adjb);
        attn_gcn_kernel<u16, float><<<dim3(1024), dim3(512), 0, stream>>>(x, x, adjb, theta, o);
    } else {
        attn_gcn_kernel<float, float><<<dim3(1024), dim3(512), 0, stream>>>(x, x, adj, theta, o);
    }
}